// Round 7
// baseline (194.977 us; speedup 1.0000x reference)
//
#include <hip/hip_runtime.h>

// HOG (64,1,512,512) f32, skimage-compatible: orientations=9, cell=8, block=2x2, L2-Hys.
// K1: per-cell 9-bin hist -> d_ws (64*64*64*9 f32). One thread = 8 px (one cell-row).
//     Two-phase body (compute all bins/mags, then atomics) + __launch_bounds__(256,4)
//     so the compiler keeps all 8 loads in flight (round-5 was starved at 24 VGPRs).
// K2: 2x2 sliding-block L2-Hys -> d_out. One 64-thr block per (img, block-row);
//     stages the two hist cell-rows in LDS via coalesced float4.

#define ORIENT 9
#define IMH 512
#define IMW 512
#define NCR 64
#define NCC 64
#define NBR 63
#define NBC 63
#define NIMG 64

// ---------------------------------------------------------------------------
// Kernel 1. block (32,8)=256 thr: 32 cells wide x 8 rows = one cell-strip.
// grid (2, 64, 64). Thread (tx,ty): pixels (r=by*8+ty, c=bx*256+tx*8 .. +7).
// ---------------------------------------------------------------------------
__global__ __launch_bounds__(256, 4) void hog_cell_hist(const float* __restrict__ img,
                                                        float* __restrict__ hist) {
    __shared__ float lh[32 * ORIENT];           // 288 floats
    const int tx = threadIdx.x;                 // 0..31  (cell in strip)
    const int ty = threadIdx.y;                 // 0..7   (row in cell)
    const int tid = ty * 32 + tx;

    lh[tid] = 0.f;
    if (tid < 32) lh[tid + 256] = 0.f;
    __syncthreads();

    const int c0 = blockIdx.x * 256 + tx * 8;
    const int r  = blockIdx.y * 8 + ty;
    const float* im = img + (size_t)blockIdx.z * (IMH * IMW) + (size_t)r * IMW + c0;

    // c0 is a multiple of 8 floats -> 32B aligned: float4 loads are safe.
    const float4* imv = (const float4*)im;
    float4 a0 = imv[0], b0 = imv[1];            // row r  [c0..c0+7]
    float4 am = {0,0,0,0}, bm = {0,0,0,0};      // row r-1
    float4 ap = {0,0,0,0}, bp = {0,0,0,0};      // row r+1
    const bool rin = (r > 0) && (r < IMH - 1);
    if (r > 0)       { const float4* p = (const float4*)(im - IMW); am = p[0]; bm = p[1]; }
    if (r < IMH - 1) { const float4* p = (const float4*)(im + IMW); ap = p[0]; bp = p[1]; }
    const float left  = (c0 > 0)       ? im[-1] : 0.f;
    const float right = (c0 + 8 < IMW) ? im[8]  : 0.f;

    // constant-indexed after unroll -> registers (no scratch)
    float rv[10] = {left, a0.x, a0.y, a0.z, a0.w, b0.x, b0.y, b0.z, b0.w, right};
    float pv[8]  = {ap.x, ap.y, ap.z, ap.w, bp.x, bp.y, bp.z, bp.w};
    float mv[8]  = {am.x, am.y, am.z, am.w, bm.x, bm.y, bm.z, bm.w};

    // Phase 1: pure VALU — 8 independent atan2 chains, full ILP.
    float mags[8];
    int   bins[8];
#pragma unroll
    for (int j = 0; j < 8; ++j) {
        const float gr = rin ? (pv[j] - mv[j]) : 0.f;                 // central diff rows
        const bool cin = (c0 + j > 0) && (c0 + j < IMW - 1);
        const float gc = cin ? (rv[j + 2] - rv[j]) : 0.f;             // central diff cols
        mags[j] = sqrtf(gr * gr + gc * gc);
        // degrees(atan2) % 180, floor-mod. |ori| <= 180.0000x so two predicated
        // fixups match fmodf+cond-add bit-for-bit (incl. ori==180 -> bin 0 for
        // the gr==+0, gc<0 border case, matching JAX 180%180==0).
        float ori = atan2f(gr, gc) * 57.29577951308232f;
        ori = (ori >= 180.0f) ? ori - 180.0f : ori;
        ori = (ori <   0.0f) ? ori + 180.0f : ori;
        int bin = (int)(ori / 20.0f);            // true division: matches XLA
        bins[j] = bin > (ORIENT - 1) ? (ORIENT - 1) : bin;
    }
    // Phase 2: flush. ds_add_f32 is fire-and-forget (return value unused).
    float* cellh = &lh[tx * ORIENT];
#pragma unroll
    for (int j = 0; j < 8; ++j) atomicAdd(&cellh[bins[j]], mags[j]);
    __syncthreads();

    // 288 contiguous floats: hist[b][by][bx*32 .. bx*32+31][0..8]
    float* hrow = hist + (((size_t)blockIdx.z * NCR + blockIdx.y) * NCC + blockIdx.x * 32) * ORIENT;
    hrow[tid] = lh[tid] * (1.f / 64.f);
    if (tid < 32) hrow[tid + 256] = lh[tid + 256] * (1.f / 64.f);
}

// ---------------------------------------------------------------------------
// Kernel 2: one 64-thread block per (image, block-row). Stage the two hist
// cell-rows (2*64*9 = 1152 floats = 4.6KB, contiguous & 16B-aligned) into LDS
// with coalesced float4, then lane bc<63 computes one descriptor.
// ---------------------------------------------------------------------------
__global__ __launch_bounds__(64) void hog_block_norm(const float* __restrict__ hist,
                                                     float* __restrict__ out) {
    __shared__ float lh[2 * NCC * ORIENT];      // 1152 floats
    const int tid = threadIdx.x;                // 0..63
    const int br  = blockIdx.x;                 // 0..62
    const int b   = blockIdx.y;                 // 0..63

    // rows br and br+1 are contiguous: base = (b*64 + br) * 576 floats
    const float4* src = (const float4*)(hist + ((size_t)b * NCR + br) * (NCC * ORIENT));
    float4* dst = (float4*)lh;
#pragma unroll
    for (int k = 0; k < 5; ++k) {               // 288 float4 / 64 threads
        int idx = k * 64 + tid;
        if (idx < 288) dst[idx] = src[idx];
    }
    __syncthreads();

    const int bc = tid;
    if (bc >= NBC) return;

    float v[36];
    float s = 0.f;
#pragma unroll
    for (int k = 0; k < 18; ++k) { float h = lh[bc * ORIENT + k];               v[k]      = h; s += h * h; }
#pragma unroll
    for (int k = 0; k < 18; ++k) { float h = lh[NCC * ORIENT + bc * ORIENT + k]; v[18 + k] = h; s += h * h; }

    const float r1 = 1.0f / sqrtf(s + 1e-10f);  // EPS^2
    float s2 = 0.f;
#pragma unroll
    for (int k = 0; k < 36; ++k) {
        float x = fminf(v[k] * r1, 0.2f);
        v[k] = x;
        s2 += x * x;
    }
    const float r2 = 1.0f / sqrtf(s2 + 1e-10f);

    float4* o = (float4*)(out + (((size_t)b * NBR + br) * NBC + bc) * 36);
#pragma unroll
    for (int k = 0; k < 9; ++k)
        o[k] = make_float4(v[4*k] * r2, v[4*k+1] * r2, v[4*k+2] * r2, v[4*k+3] * r2);
}

// ---------------------------------------------------------------------------
extern "C" void kernel_launch(void* const* d_in, const int* in_sizes, int n_in,
                              void* d_out, int out_size, void* d_ws, size_t ws_size,
                              hipStream_t stream) {
    const float* x = (const float*)d_in[0];
    float* out  = (float*)d_out;
    float* hist = (float*)d_ws;                 // 64*64*64*9 f32 = 9.44 MB

    dim3 b1(32, 8, 1);
    dim3 g1(IMW / 256, IMH / 8, NIMG);          // (2, 64, 64)
    hipLaunchKernelGGL(hog_cell_hist, g1, b1, 0, stream, x, hist);

    dim3 b2(64, 1, 1);
    dim3 g2(NBR, NIMG, 1);                      // (63, 64)
    hipLaunchKernelGGL(hog_block_norm, g2, b2, 0, stream, hist, out);
}

// Round 8
// 187.501 us; speedup vs baseline: 1.0399x; 1.0399x over previous
//
#include <hip/hip_runtime.h>

// HOG (64,1,512,512) f32, skimage-compatible: orientations=9, cell=8, block=2x2, L2-Hys.
// K1: per-cell 9-bin hist -> d_ws. One thread = 16 px (2 adjacent rows of one cell):
//     4 loaded rows serve 2 gradient rows (VMEM/px 1.25->0.75), addressing amortized.
//     Binning math bit-identical to prior passing rounds (ocml atan2f + true /20.0f);
//     only sqrtf -> v_sqrt_f32 (<=1ulp, feeds continuous sums only).
// K2: 2x2 sliding-block L2-Hys -> d_out (unchanged from round 7; ~small vs K1).

#define ORIENT 9
#define IMH 512
#define IMW 512
#define NCR 64
#define NCC 64
#define NBR 63
#define NBC 63
#define NIMG 64

#if defined(__has_builtin)
#if __has_builtin(__builtin_amdgcn_sqrtf)
#define FAST_SQRT(x) __builtin_amdgcn_sqrtf(x)
#else
#define FAST_SQRT(x) sqrtf(x)
#endif
#else
#define FAST_SQRT(x) sqrtf(x)
#endif

// ---------------------------------------------------------------------------
// Kernel 1. block (32,4)=128 thr: 32 cells wide x 4 row-pairs = one cell-strip.
// grid (2, 64, 64). Thread (tx,ty): rows rA=by*8+ty*2, rA+1; cols bx*256+tx*8..+7.
// ---------------------------------------------------------------------------
__global__ __launch_bounds__(128) void hog_cell_hist(const float* __restrict__ img,
                                                     float* __restrict__ hist) {
    __shared__ float lh[32 * ORIENT];           // 288 floats
    const int tx = threadIdx.x;                 // 0..31  (cell in strip)
    const int ty = threadIdx.y;                 // 0..3   (row-pair in cell)
    const int tid = ty * 32 + tx;               // 0..127

    lh[tid] = 0.f;
    lh[tid + 128] = 0.f;
    if (tid < 32) lh[tid + 256] = 0.f;
    __syncthreads();

    const int c0 = blockIdx.x * 256 + tx * 8;
    const int rA = blockIdx.y * 8 + ty * 2;     // rows rA, rA+1; rA in [0,510]
    const float* im = img + (size_t)blockIdx.z * (IMH * IMW) + (size_t)rA * IMW + c0;

    // c0 multiple of 8 floats -> 32B aligned: float4 loads safe.
    const float4* p0 = (const float4*)im;             // row rA
    const float4* p1 = (const float4*)(im + IMW);     // row rA+1
    float4 r0a = p0[0], r0b = p0[1];
    float4 r1a = p1[0], r1b = p1[1];
    float4 rma = {0,0,0,0}, rmb = {0,0,0,0};          // row rA-1
    float4 r2a = {0,0,0,0}, r2b = {0,0,0,0};          // row rA+2
    if (rA > 0)       { const float4* p = (const float4*)(im - IMW);     rma = p[0]; rmb = p[1]; }
    if (rA + 2 < IMH) { const float4* p = (const float4*)(im + 2 * IMW); r2a = p[0]; r2b = p[1]; }
    const bool cle = (c0 > 0), cri = (c0 + 8 < IMW);
    const float lA = cle ? im[-1]      : 0.f;
    const float rAs = cri ? im[8]       : 0.f;
    const float lB = cle ? im[IMW - 1] : 0.f;
    const float rBs = cri ? im[IMW + 8] : 0.f;

    const bool rinA = (rA > 0);                 // rA < 511 always
    const bool rinB = (rA + 2 < IMH);           // rA+1 > 0 always

    float* cellh = &lh[tx * ORIENT];

    // ---- pixel row rA: up = rA-1, down = rA+1 ----
    {
        float rv[10] = {lA, r0a.x,r0a.y,r0a.z,r0a.w, r0b.x,r0b.y,r0b.z,r0b.w, rAs};
        float up[8]  = {rma.x,rma.y,rma.z,rma.w, rmb.x,rmb.y,rmb.z,rmb.w};
        float dn[8]  = {r1a.x,r1a.y,r1a.z,r1a.w, r1b.x,r1b.y,r1b.z,r1b.w};
        float mags[8]; int bins[8];
#pragma unroll
        for (int j = 0; j < 8; ++j) {
            const float gr = rinA ? (dn[j] - up[j]) : 0.f;
            const bool cin = (c0 + j > 0) && (c0 + j < IMW - 1);
            const float gc = cin ? (rv[j + 2] - rv[j]) : 0.f;
            mags[j] = FAST_SQRT(gr * gr + gc * gc);
            // degrees(atan2) floor-mod 180 — bit-identical to passing rounds.
            float ori = atan2f(gr, gc) * 57.29577951308232f;
            ori = (ori >= 180.0f) ? ori - 180.0f : ori;
            ori = (ori <   0.0f) ? ori + 180.0f : ori;
            int bin = (int)(ori / 20.0f);        // true division: matches XLA
            bins[j] = bin > (ORIENT - 1) ? (ORIENT - 1) : bin;
        }
#pragma unroll
        for (int j = 0; j < 8; ++j) atomicAdd(&cellh[bins[j]], mags[j]);
    }
    // ---- pixel row rA+1: up = rA, down = rA+2 ----
    {
        float rv[10] = {lB, r1a.x,r1a.y,r1a.z,r1a.w, r1b.x,r1b.y,r1b.z,r1b.w, rBs};
        float up[8]  = {r0a.x,r0a.y,r0a.z,r0a.w, r0b.x,r0b.y,r0b.z,r0b.w};
        float dn[8]  = {r2a.x,r2a.y,r2a.z,r2a.w, r2b.x,r2b.y,r2b.z,r2b.w};
        float mags[8]; int bins[8];
#pragma unroll
        for (int j = 0; j < 8; ++j) {
            const float gr = rinB ? (dn[j] - up[j]) : 0.f;
            const bool cin = (c0 + j > 0) && (c0 + j < IMW - 1);
            const float gc = cin ? (rv[j + 2] - rv[j]) : 0.f;
            mags[j] = FAST_SQRT(gr * gr + gc * gc);
            float ori = atan2f(gr, gc) * 57.29577951308232f;
            ori = (ori >= 180.0f) ? ori - 180.0f : ori;
            ori = (ori <   0.0f) ? ori + 180.0f : ori;
            int bin = (int)(ori / 20.0f);
            bins[j] = bin > (ORIENT - 1) ? (ORIENT - 1) : bin;
        }
#pragma unroll
        for (int j = 0; j < 8; ++j) atomicAdd(&cellh[bins[j]], mags[j]);
    }
    __syncthreads();

    // 288 contiguous floats: hist[b][by][bx*32 .. +31][0..8]
    float* hrow = hist + (((size_t)blockIdx.z * NCR + blockIdx.y) * NCC + blockIdx.x * 32) * ORIENT;
    hrow[tid]       = lh[tid]       * (1.f / 64.f);
    hrow[tid + 128] = lh[tid + 128] * (1.f / 64.f);
    if (tid < 32) hrow[tid + 256] = lh[tid + 256] * (1.f / 64.f);
}

// ---------------------------------------------------------------------------
// Kernel 2 (unchanged from round 7): one 64-thread block per (image, block-row).
// ---------------------------------------------------------------------------
__global__ __launch_bounds__(64) void hog_block_norm(const float* __restrict__ hist,
                                                     float* __restrict__ out) {
    __shared__ float lh[2 * NCC * ORIENT];      // 1152 floats
    const int tid = threadIdx.x;                // 0..63
    const int br  = blockIdx.x;                 // 0..62
    const int b   = blockIdx.y;                 // 0..63

    const float4* src = (const float4*)(hist + ((size_t)b * NCR + br) * (NCC * ORIENT));
    float4* dst = (float4*)lh;
#pragma unroll
    for (int k = 0; k < 5; ++k) {               // 288 float4 / 64 threads
        int idx = k * 64 + tid;
        if (idx < 288) dst[idx] = src[idx];
    }
    __syncthreads();

    const int bc = tid;
    if (bc >= NBC) return;

    float v[36];
    float s = 0.f;
#pragma unroll
    for (int k = 0; k < 18; ++k) { float h = lh[bc * ORIENT + k];                v[k]      = h; s += h * h; }
#pragma unroll
    for (int k = 0; k < 18; ++k) { float h = lh[NCC * ORIENT + bc * ORIENT + k]; v[18 + k] = h; s += h * h; }

    const float r1 = 1.0f / sqrtf(s + 1e-10f);  // EPS^2
    float s2 = 0.f;
#pragma unroll
    for (int k = 0; k < 36; ++k) {
        float x = fminf(v[k] * r1, 0.2f);
        v[k] = x;
        s2 += x * x;
    }
    const float r2 = 1.0f / sqrtf(s2 + 1e-10f);

    float4* o = (float4*)(out + (((size_t)b * NBR + br) * NBC + bc) * 36);
#pragma unroll
    for (int k = 0; k < 9; ++k)
        o[k] = make_float4(v[4*k] * r2, v[4*k+1] * r2, v[4*k+2] * r2, v[4*k+3] * r2);
}

// ---------------------------------------------------------------------------
extern "C" void kernel_launch(void* const* d_in, const int* in_sizes, int n_in,
                              void* d_out, int out_size, void* d_ws, size_t ws_size,
                              hipStream_t stream) {
    const float* x = (const float*)d_in[0];
    float* out  = (float*)d_out;
    float* hist = (float*)d_ws;                 // 64*64*64*9 f32 = 9.44 MB

    dim3 b1(32, 4, 1);
    dim3 g1(IMW / 256, NCR, NIMG);              // (2, 64, 64)
    hipLaunchKernelGGL(hog_cell_hist, g1, b1, 0, stream, x, hist);

    dim3 b2(64, 1, 1);
    dim3 g2(NBR, NIMG, 1);                      // (63, 64)
    hipLaunchKernelGGL(hog_block_norm, g2, b2, 0, stream, hist, out);
}